// Round 12
// baseline (281.369 us; speedup 1.0000x reference)
//
#include <hip/hip_runtime.h>
#include <cstdint>

#define NN 50000
#define NE 600000

typedef unsigned short ushort_t;
typedef __bf16 bf16_t;
typedef __attribute__((ext_vector_type(8))) bf16_t bf16x8;
typedef __attribute__((ext_vector_type(8))) ushort_t ushort8;
typedef __attribute__((ext_vector_type(4))) float f32x4;

// ---- ws layout (float offsets), extent 19,341,472 fl = 77.37 MB ----
// WTf  : [10 iter][8 q][128 col][8] bf16 @ 0    (81,920 ushorts = 40,960 fl)
// XG   : [3125 tiles][80 g][16 rows][8] bf16 @ 40,960   (32M ushorts = 16M fl)
//        g 0..15 = X k-cols 0..127; g 16..79 = G (4 bases x 128), kk = g*8
// Xbf  : [NN][128] bf16 (node-major, gather source) @ 16,040,960  (3.2M fl)
// cnt  : [NN] i32                   @ 19,240,960
// curs : [NN] i32                   @ 19,290,960
// bsum/bscan : 128+128 i32          @ 19,340,960 / 19,341,088
// colsum/colsq : 128+128 f32        @ 19,341,216 / 19,341,344
#define WT_OFF   0ul
#define XG_OFF   40960ul
#define XBF_OFF  16040960ul
#define CNT_OFF  19240960ul
#define CUR_OFF  19290960ul
#define BSUM_OFF 19340960ul
#define BSCN_OFF 19341088ul
#define CS_OFF   19341216ul
#define CSQ_OFF  19341344ul
// d_out transient: epack [NE] u32 @ 0 (scatter -> gather; dead before k_gemm_f)

__device__ __forceinline__ float2 bf2_to_f2(uint32_t u) {
    float2 r;
    r.x = __uint_as_float(u << 16);
    r.y = __uint_as_float(u & 0xffff0000u);
    return r;
}

__device__ __forceinline__ ushort_t f2bf(float f) {
    uint32_t u = __float_as_uint(f);
    u = (u + 0x7fffu + ((u >> 16) & 1u)) >> 16;   // RNE
    return (ushort_t)u;
}

__device__ __forceinline__ uint32_t f2bf2(float x, float y) {
    return (uint32_t)f2bf(x) | ((uint32_t)f2bf(y) << 16);
}

__device__ __forceinline__ void async_copy16(const void* g, void* l) {
    __builtin_amdgcn_global_load_lds(
        (const __attribute__((address_space(1))) void*)g,
        (__attribute__((address_space(3))) void*)l, 16, 0, 0);
}

// ---------------------------------------------------------------------------
// K0: WTf[it][q][n][j] = W[k = it*64+q*8+j][n];  W = [Wl ; bases] (K=640).
// Per-iter 16KB contiguous -> async-stageable; ds_read banks 2-way (free).
// ---------------------------------------------------------------------------
__global__ __launch_bounds__(256) void k_prep(
    const float* __restrict__ Wl, const float* __restrict__ bases,
    ushort_t* __restrict__ WTf)
{
    const int i = blockIdx.x * 256 + threadIdx.x;
    if (i >= 81920) return;
    const int it = i >> 13;
    const int r1 = i & 8191;
    const int q = r1 >> 10;
    const int r2 = r1 & 1023;
    const int n = r2 >> 3;
    const int j = r2 & 7;
    const int k = it * 64 + q * 8 + j;
    float v;
    if (k < 128) v = Wl[k * 128 + n];
    else {
        const int jj = k - 128;
        v = bases[(size_t)(jj >> 7) * 16384 + (jj & 127) * 128 + n];
    }
    WTf[i] = f2bf(v);
}

// ---------------------------------------------------------------------------
// K0b: per 16-node tile: write Xbf (node-major) + XG X-part (fragment order)
// via an LDS transpose.
// ---------------------------------------------------------------------------
__global__ __launch_bounds__(256) void k_cast(
    const float* __restrict__ X, ushort_t* __restrict__ Xbf,
    ushort_t* __restrict__ XG)
{
    __shared__ ushort_t L[16][136];
    const int tid = threadIdx.x;
    const int tile = blockIdx.x;
    {
        const int row = tid >> 4, gc = tid & 15;
        const int node = tile * 16 + row;           // grid=3125 -> node<NN
        const float4* p = (const float4*)(X + (size_t)node * 128 + gc * 8);
        const float4 a = p[0], b = p[1];
        ushort_t t8[8] = { f2bf(a.x), f2bf(a.y), f2bf(a.z), f2bf(a.w),
                           f2bf(b.x), f2bf(b.y), f2bf(b.z), f2bf(b.w) };
        const uint4 v = *(const uint4*)t8;
        *(uint4*)&L[row][gc * 8] = v;
        *(uint4*)(Xbf + (size_t)node * 128 + gc * 8) = v;   // coalesced
    }
    __syncthreads();
    {
        const int g = tid >> 4, r2 = tid & 15;
        const uint4 u = *(const uint4*)&L[r2][g * 8];
        *(uint4*)(XG + (size_t)tile * 10240 + g * 128 + r2 * 8) = u;
    }
}

// ---------------------------------------------------------------------------
// K2: histogram of dst -> cnt
// ---------------------------------------------------------------------------
__global__ __launch_bounds__(256) void k_hist(
    const int* __restrict__ eidx, int* __restrict__ cnt)
{
    const int* __restrict__ dst = eidx + NE;
    for (int e = blockIdx.x * 256 + threadIdx.x; e < NE; e += gridDim.x * 256)
        atomicAdd(cnt + dst[e], 1);
}

// ---------------------------------------------------------------------------
// K3a/b/c: exclusive scan of cnt -> curs
// ---------------------------------------------------------------------------
__global__ __launch_bounds__(256) void k_scan1(
    const int* __restrict__ cnt, int* __restrict__ curs, int* __restrict__ bsum)
{
    __shared__ int sh[256];
    const int tid = threadIdx.x;
    const int i0 = blockIdx.x * 512 + tid * 2;
    const int v0 = (i0 < NN) ? cnt[i0] : 0;
    const int v1 = (i0 + 1 < NN) ? cnt[i0 + 1] : 0;
    int s = v0 + v1;
    sh[tid] = s;
    __syncthreads();
#pragma unroll
    for (int off = 1; off < 256; off <<= 1) {
        int t = (tid >= off) ? sh[tid - off] : 0;
        __syncthreads();
        sh[tid] += t;
        __syncthreads();
    }
    const int excl = sh[tid] - s;
    if (i0 < NN) curs[i0] = excl;
    if (i0 + 1 < NN) curs[i0 + 1] = excl + v0;
    if (tid == 255) bsum[blockIdx.x] = sh[255];
}

__global__ __launch_bounds__(128) void k_scan2(
    const int* __restrict__ bsum, int* __restrict__ bscan, int nblk)
{
    __shared__ int sh[128];
    const int tid = threadIdx.x;
    int v = (tid < nblk) ? bsum[tid] : 0;
    sh[tid] = v;
    __syncthreads();
#pragma unroll
    for (int off = 1; off < 128; off <<= 1) {
        int t = (tid >= off) ? sh[tid - off] : 0;
        __syncthreads();
        sh[tid] += t;
        __syncthreads();
    }
    if (tid < nblk) bscan[tid] = sh[tid] - v;
}

__global__ __launch_bounds__(256) void k_scan3(
    int* __restrict__ curs, const int* __restrict__ bscan)
{
    const int add = bscan[blockIdx.x];
    const int i0 = blockIdx.x * 512 + threadIdx.x * 2;
    if (i0 < NN) curs[i0] += add;
    if (i0 + 1 < NN) curs[i0 + 1] += add;
}

// ---------------------------------------------------------------------------
// K4: scatter edges into CSR slots. epack = src | (type<<16).
// ---------------------------------------------------------------------------
__global__ __launch_bounds__(256) void k_scatter(
    const int* __restrict__ eidx, const int* __restrict__ etype,
    int* __restrict__ curs, uint32_t* __restrict__ epack)
{
    const int* __restrict__ src = eidx;
    const int* __restrict__ dst = eidx + NE;
    for (int e = blockIdx.x * 256 + threadIdx.x; e < NE; e += gridDim.x * 256) {
        const int d = dst[e];
        const int pos = atomicAdd(curs + d, 1);
        epack[pos] = (uint32_t)src[e] | ((uint32_t)etype[e] << 16);
    }
}

// ---------------------------------------------------------------------------
// K5: gather, subgroup-parallel. 16 lanes per node, 4 nodes per wave.
// Lane k owns cols 8k..8k+7; full 64B lines written whole.
// ---------------------------------------------------------------------------
__device__ __forceinline__ void edge_accum8(
    uint32_t ep, const ushort_t* __restrict__ Xbf,
    const float* __restrict__ coeff, int k, float* m)   // m[32]
{
    const int s = ep & 0xffff;
    const int t = ep >> 16;
    const float4 cw = *(const float4*)(coeff + t * 4);
    const uint4 xv = *(const uint4*)(Xbf + (size_t)s * 128 + k * 8);
    float x[8];
    float2 p;
    p = bf2_to_f2(xv.x); x[0] = p.x; x[1] = p.y;
    p = bf2_to_f2(xv.y); x[2] = p.x; x[3] = p.y;
    p = bf2_to_f2(xv.z); x[4] = p.x; x[5] = p.y;
    p = bf2_to_f2(xv.w); x[6] = p.x; x[7] = p.y;
#pragma unroll
    for (int c = 0; c < 8; ++c) {
        m[0 * 8 + c] += cw.x * x[c];
        m[1 * 8 + c] += cw.y * x[c];
        m[2 * 8 + c] += cw.z * x[c];
        m[3 * 8 + c] += cw.w * x[c];
    }
}

__global__ __launch_bounds__(256) void k_gather(
    const ushort_t* __restrict__ Xbf, const uint32_t* __restrict__ epack,
    const int* __restrict__ cnt, const int* __restrict__ curs,
    const float* __restrict__ coeff, ushort_t* __restrict__ XG)
{
    const int lane = threadIdx.x & 63;
    const int w = threadIdx.x >> 6;
    const int sub = lane >> 4;     // node within wave's 4
    const int k = lane & 15;       // col block (8 cols)
    const int tile = blockIdx.x;
    const int d = tile * 16 + w * 4 + sub;   // grid=3125 -> d<NN

    const int n = cnt[d];
    const int end = curs[d];       // post-scatter: end offset
    int j = end - n;

    float m[32];
#pragma unroll
    for (int i = 0; i < 32; ++i) m[i] = 0.f;

    for (; j + 3 < end; j += 4) {
        const uint32_t e0 = epack[j];
        const uint32_t e1 = epack[j + 1];
        const uint32_t e2 = epack[j + 2];
        const uint32_t e3 = epack[j + 3];
        edge_accum8(e0, Xbf, coeff, k, m);
        edge_accum8(e1, Xbf, coeff, k, m);
        edge_accum8(e2, Xbf, coeff, k, m);
        edge_accum8(e3, Xbf, coeff, k, m);
    }
    for (; j < end; ++j) edge_accum8(epack[j], Xbf, coeff, k, m);

    uint32_t* gb = (uint32_t*)(XG + (size_t)tile * 10240);
#pragma unroll
    for (int b = 0; b < 4; ++b) {
        uint4 v;
        v.x = f2bf2(m[b * 8 + 0], m[b * 8 + 1]);
        v.y = f2bf2(m[b * 8 + 2], m[b * 8 + 3]);
        v.z = f2bf2(m[b * 8 + 4], m[b * 8 + 5]);
        v.w = f2bf2(m[b * 8 + 6], m[b * 8 + 7]);
        *(uint4*)(gb + (16 + b * 16 + k) * 64 + (w * 4 + sub) * 4) = v;
    }
}

// ---------------------------------------------------------------------------
// K6: FUSED projection, m97-style double-buffered K-loop.
// Block = 64 rows (4 XG tiles) x 128 cols; K=640 in 10 iters of BK=64.
// Per iter: stage A (8KB) + B (16KB) via async global_load_lds into the
// other buffer while computing current. LDS 2 x 24KB = 48KB -> 3 blocks/CU.
// Wave = 32 rows (rh) x 64 cols (chh): per iter 12 ds_read_b128 + 16 MFMA.
// LDS layouts lane-linear (HW dest constraint); read banks 2-way = free.
// Epilogue folds degree-norm + column stats.
// ---------------------------------------------------------------------------
__device__ __forceinline__ void stage_iter(
    const ushort_t* __restrict__ XG, const ushort_t* __restrict__ WTf,
    ushort_t* __restrict__ Lbuf, int tile0, int it, int w, int lane)
{
#pragma unroll
    for (int c6 = 0; c6 < 6; ++c6) {
        const int c = w * 6 + c6;
        if (c < 8) {                        // A: rt = c>>1, half = c&1
            const int rt = c >> 1, hf = c & 1;
            const ushort_t* src = XG + (size_t)(tile0 + rt) * 10240
                                 + it * 1024 + hf * 512 + lane * 8;
            async_copy16(src, Lbuf + rt * 1024 + hf * 512);
        } else {                            // B: q = (c-8)>>1, half = (c-8)&1
            const int cb = c - 8, q = cb >> 1, hf = cb & 1;
            const ushort_t* src = WTf + it * 8192 + q * 1024 + hf * 512 + lane * 8;
            async_copy16(src, Lbuf + 4096 + q * 1024 + hf * 512);
        }
    }
}

__global__ __launch_bounds__(256) void k_gemm_f(
    const ushort_t* __restrict__ XG, const ushort_t* __restrict__ WTf,
    const float* __restrict__ bl, const int* __restrict__ cnt,
    float* __restrict__ out, float* __restrict__ colsum,
    float* __restrict__ colsq)
{
    __shared__ ushort_t L[2][12288];   // [buf][A 4096u | B 8192u] = 24KB each
    const int tid = threadIdx.x;
    const int lane = tid & 63;
    const int w = tid >> 6;
    const int row0 = blockIdx.x * 64;
    const int tile0 = blockIdx.x * 4;
    const int m = lane & 15;
    const int quad = lane >> 4;
    const int rh = w & 1;              // row half (32 rows)
    const int chh = w >> 1;            // col half (64 cols)

    f32x4 acc[2][4];
#pragma unroll
    for (int t = 0; t < 2; ++t)
#pragma unroll
        for (int ct = 0; ct < 4; ++ct)
#pragma unroll
            for (int i = 0; i < 4; ++i) acc[t][ct][i] = 0.f;

    stage_iter(XG, WTf, L[0], tile0, 0, w, lane);
    __syncthreads();

    for (int it = 0; it < 10; ++it) {
        const int pb = it & 1;
        if (it < 9) stage_iter(XG, WTf, L[pb ^ 1], tile0, it + 1, w, lane);

#pragma unroll
        for (int kc = 0; kc < 2; ++kc) {
            const int qoff = kc * 4 + quad;
            bf16x8 a[2], b[4];
#pragma unroll
            for (int t = 0; t < 2; ++t)
                a[t] = __builtin_bit_cast(bf16x8, *(const ushort8*)
                    &L[pb][(rh * 2 + t) * 1024 + qoff * 128 + m * 8]);
#pragma unroll
            for (int ct = 0; ct < 4; ++ct)
                b[ct] = __builtin_bit_cast(bf16x8, *(const ushort8*)
                    &L[pb][4096 + qoff * 1024 + (chh * 64 + ct * 16 + m) * 8]);
#pragma unroll
            for (int t = 0; t < 2; ++t)
#pragma unroll
                for (int ct = 0; ct < 4; ++ct)
                    acc[t][ct] = __builtin_amdgcn_mfma_f32_16x16x32_bf16(
                        a[t], b[ct], acc[t][ct], 0, 0, 0);
        }
        __syncthreads();
    }

    // epilogue: degree-norm, store, column stats
    float blv[4], ss[4], qq[4];
#pragma unroll
    for (int ct = 0; ct < 4; ++ct) {
        blv[ct] = bl[chh * 64 + ct * 16 + m];
        ss[ct] = 0.f; qq[ct] = 0.f;
    }

#pragma unroll
    for (int t = 0; t < 2; ++t) {
        const int rowb = row0 + rh * 32 + t * 16 + quad * 4;
#pragma unroll
        for (int r = 0; r < 4; ++r) {
            const int row = rowb + r;
            if (row < NN) {
                const int dg = cnt[row];
                const float inv = 1.0f / (float)((dg > 0) ? dg : 1);
                float* po = out + (size_t)row * 128 + chh * 64 + m;
#pragma unroll
                for (int ct = 0; ct < 4; ++ct) {
                    const float v = (acc[t][ct][r] + blv[ct]) * inv;
                    po[ct * 16] = v;
                    ss[ct] += v; qq[ct] += v * v;
                }
            }
        }
    }

#pragma unroll
    for (int ct = 0; ct < 4; ++ct) {
        ss[ct] += __shfl_down(ss[ct], 32); qq[ct] += __shfl_down(qq[ct], 32);
        ss[ct] += __shfl_down(ss[ct], 16); qq[ct] += __shfl_down(qq[ct], 16);
    }
    if (lane < 16) {
#pragma unroll
        for (int ct = 0; ct < 4; ++ct) {
            atomicAdd(colsum + chh * 64 + ct * 16 + lane, ss[ct]);
            atomicAdd(colsq  + chh * 64 + ct * 16 + lane, qq[ct]);
        }
    }
}

// ---------------------------------------------------------------------------
// K7: BatchNorm (batch stats) + ReLU, in place on d_out.
// ---------------------------------------------------------------------------
__global__ __launch_bounds__(256) void k_bn_relu(
    float* __restrict__ out, const float* __restrict__ colsum,
    const float* __restrict__ colsq, const float* __restrict__ gamma,
    const float* __restrict__ beta)
{
    __shared__ float sc[128], sh[128];
    const int tid = threadIdx.x;
    if (tid < 128) {
        const float mean = colsum[tid] * (1.0f / NN);
        const float var = colsq[tid] * (1.0f / NN) - mean * mean;
        const float g = gamma[tid] * rsqrtf(var + 1e-5f);
        sc[tid] = g;
        sh[tid] = beta[tid] - mean * g;
    }
    __syncthreads();
    const int total = NN * 32;
    for (int i = blockIdx.x * 256 + tid; i < total; i += gridDim.x * 256) {
        const int c = (i & 31) << 2;
        float4 v = *(float4*)(out + (size_t)i * 4);
        v.x = fmaxf(fmaf(v.x, sc[c + 0], sh[c + 0]), 0.f);
        v.y = fmaxf(fmaf(v.y, sc[c + 1], sh[c + 1]), 0.f);
        v.z = fmaxf(fmaf(v.z, sc[c + 2], sh[c + 2]), 0.f);
        v.w = fmaxf(fmaf(v.w, sc[c + 3], sh[c + 3]), 0.f);
        *(float4*)(out + (size_t)i * 4) = v;
    }
}

extern "C" void kernel_launch(void* const* d_in, const int* in_sizes, int n_in,
                              void* d_out, int out_size, void* d_ws, size_t ws_size,
                              hipStream_t stream)
{
    const float* X      = (const float*)d_in[0];
    const float* bases  = (const float*)d_in[1];
    const float* coeff  = (const float*)d_in[2];
    const float* Wl     = (const float*)d_in[3];
    const float* bl     = (const float*)d_in[4];
    const float* gamma  = (const float*)d_in[5];
    const float* beta   = (const float*)d_in[6];
    const int*   eidx   = (const int*)d_in[7];
    const int*   etype  = (const int*)d_in[8];
    float* out = (float*)d_out;

    float* ws = (float*)d_ws;
    ushort_t* WTf    = (ushort_t*)(ws + WT_OFF);
    ushort_t* XG     = (ushort_t*)(ws + XG_OFF);
    ushort_t* Xbf    = (ushort_t*)(ws + XBF_OFF);
    int*      cnt    = (int*)(ws + CNT_OFF);
    int*      curs   = (int*)(ws + CUR_OFF);
    int*      bsum   = (int*)(ws + BSUM_OFF);
    int*      bscan  = (int*)(ws + BSCN_OFF);
    float*    colsum = ws + CS_OFF;
    float*    colsq  = ws + CSQ_OFF;
    uint32_t* epack  = (uint32_t*)d_out;   // dead before k_gemm_f writes out

    // zero cnt..colsq
    hipMemsetAsync(cnt, 0, (CSQ_OFF + 128 - CNT_OFF) * sizeof(float), stream);

    const int nblk_scan = (NN + 511) / 512;   // 98

    k_prep<<<(81920 + 255) / 256, 256, 0, stream>>>(Wl, bases, WTf);
    k_cast<<<3125, 256, 0, stream>>>(X, Xbf, XG);
    k_hist<<<512, 256, 0, stream>>>(eidx, cnt);
    k_scan1<<<nblk_scan, 256, 0, stream>>>(cnt, curs, bsum);
    k_scan2<<<1, 128, 0, stream>>>(bsum, bscan, nblk_scan);
    k_scan3<<<nblk_scan, 256, 0, stream>>>(curs, bscan);
    k_scatter<<<512, 256, 0, stream>>>(eidx, etype, curs, epack);
    k_gather<<<3125, 256, 0, stream>>>(Xbf, epack, cnt, curs, coeff, XG);
    k_gemm_f<<<(NN + 63) / 64, 256, 0, stream>>>(
        XG, WTf, bl, cnt, out, colsum, colsq);
    k_bn_relu<<<1024, 256, 0, stream>>>(out, colsum, colsq, gamma, beta);
}